// Round 16
// baseline (244.395 us; speedup 1.0000x reference)
//
#include <hip/hip_runtime.h>
#include <math.h>

#define NPTS  16384
#define KNN   16
#define SEQV  8
#define NW    16      // waves per block (= partitions per query)
#define SLICE 1024    // candidates per wave slice
#define RUN   256     // cold-sampled per slice in K1 -> 4096-sample
#define BATCH 8
#define CAPM  15      // mega append words/thread (flush thr 7; E[acc]=4 -> safe)

__device__ __forceinline__ unsigned umin_(unsigned a, unsigned b) { return a < b ? a : b; }
__device__ __forceinline__ unsigned umax_(unsigned a, unsigned b) { return a > b ? a : b; }

// merge one key into sorted ascending keys[16]
__device__ __forceinline__ void merge_one(unsigned keys[KNN], unsigned kk) {
    if (kk < keys[KNN - 1]) {
#pragma unroll
        for (int u = 0; u < KNN; ++u) {
            unsigned lo = umin_(kk, keys[u]);
            kk = umax_(kk, keys[u]);
            keys[u] = lo;
        }
    }
}

// ---------------------------------------------------------------------------
// K1: 4096-sample tau. Grid 256 x 1024 (16 waves, 4/SIMD, 1 block/CU).
// Wave wv cold-chains the first RUN=256 candidates of chunk [1024*wv, ...)
// for the block's 64 queries (lane = query). 4-round stride-16 LDS tree
// merge (2-way bank aliasing = free) -> tau over the 4096-sample
// (>= global 16th => exact filter; tight enough that mega's CAP=15 buffers
// flush rarely: accept p ~ 1/256). Also writes pc4 and zeroes accum.
// key = (d2 bits & 0xFFFFC000) | j  (j < 2^14).
// ---------------------------------------------------------------------------
__global__ __launch_bounds__(1024, 4) void sample_tau_kernel(
    const float* __restrict__ pc, float4* __restrict__ pc4,
    float* __restrict__ taufArr, float* __restrict__ accum)
{
    __shared__ unsigned sK[1024 * 16];   // 64 KB exactly

    const int tid  = threadIdx.x;
    const int lane = tid & 63;
    const int wv   = __builtin_amdgcn_readfirstlane(tid >> 6);   // 0..15
    const int i    = blockIdx.x * 64 + lane;

    if (blockIdx.x == 0 && tid == 0) {
        accum[0] = 0.0f; accum[1] = 0.0f;
        ((unsigned*)accum)[2] = 0u; ((unsigned*)accum)[3] = 0u;
    }

    const float qx = pc[3 * i + 0];
    const float qy = pc[3 * i + 1];
    const float qz = pc[3 * i + 2];
    const float q2 = fmaf(qx, qx, fmaf(qy, qy, qz * qz));

    if (wv == 0) pc4[i] = make_float4(qx, qy, qz, q2);

    unsigned keys[KNN];
#pragma unroll
    for (int t = 0; t < KNN; ++t) keys[t] = 0xFFFFFFFFu;

    const int jbeg = wv * SLICE;
    const float* cb = pc + 3 * (size_t)jbeg;      // wave-uniform -> s_load

    float A[3 * BATCH], B[3 * BATCH];
#pragma unroll
    for (int u = 0; u < 3 * BATCH; ++u) A[u] = cb[u];

    auto process = [&](const float* C, int jbase) {
        unsigned kb[BATCH];
#pragma unroll
        for (int q = 0; q < BATCH; ++q) {
            float dx = qx - C[3 * q + 0];
            float dy = qy - C[3 * q + 1];
            float dz = qz - C[3 * q + 2];
            float d2 = fmaf(dx, dx, fmaf(dy, dy, dz * dz));
            kb[q] = (__float_as_uint(d2) & 0xFFFFC000u)
                  | (unsigned)(jbeg + jbase + q);
        }
#pragma unroll
        for (int q = 0; q < BATCH; ++q) merge_one(keys, kb[q]);
    };

#pragma unroll 1
    for (int jo = 0; jo < RUN; jo += 2 * BATCH) {
#pragma unroll
        for (int u = 0; u < 3 * BATCH; ++u) B[u] = cb[3 * (jo + BATCH) + u];
        process(A, jo);
        if (jo + 2 * BATCH < RUN) {
#pragma unroll
            for (int u = 0; u < 3 * BATCH; ++u) A[u] = cb[3 * (jo + 2 * BATCH) + u];
        }
        process(B, jo + BATCH);
    }

    // ---- 4-round tree merge (16 -> 1 lists per query) ----
#pragma unroll
    for (int t = 0; t < KNN; ++t) sK[tid * 16 + t] = keys[t];
    __syncthreads();
    if (wv < 8) {
        const unsigned* p = &sK[(tid + 512) * 16];
#pragma unroll
        for (int t = 0; t < KNN; ++t) merge_one(keys, p[t]);
#pragma unroll
        for (int t = 0; t < KNN; ++t) sK[tid * 16 + t] = keys[t];
    }
    __syncthreads();
    if (wv < 4) {
        const unsigned* p = &sK[(tid + 256) * 16];
#pragma unroll
        for (int t = 0; t < KNN; ++t) merge_one(keys, p[t]);
#pragma unroll
        for (int t = 0; t < KNN; ++t) sK[tid * 16 + t] = keys[t];
    }
    __syncthreads();
    if (wv < 2) {
        const unsigned* p = &sK[(tid + 128) * 16];
#pragma unroll
        for (int t = 0; t < KNN; ++t) merge_one(keys, p[t]);
#pragma unroll
        for (int t = 0; t < KNN; ++t) sK[tid * 16 + t] = keys[t];
    }
    __syncthreads();
    if (wv == 0) {
        const unsigned* p = &sK[(tid + 64) * 16];
#pragma unroll
        for (int t = 0; t < KNN; ++t) merge_one(keys, p[t]);
        const float d16 = __uint_as_float(keys[KNN - 1] & 0xFFFFC000u);
        // margin covers fma/truncation rounding -> provably exact filter
        taufArr[i] = fmaf(d16, 1.0002f, 1e-6f) - q2;
    }
}

// ---------------------------------------------------------------------------
// K2: mega = filtered scan + tree merge + radius + loss + finalize.
// Grid 256 x 1024 (1 block/CU, 4 waves/SIMD — R9's proven concurrency).
// Block owns queries [64bx, 64bx+64) (lane = query); wave wv scans slice
// [1024wv, +1024) with the R9 scan (SGPR batches, ping-pong, exec-masked
// LDS append, flush-tighten). CAP=15 is safe because tau comes from the
// 4096-sample (E[accepts]=4, flush thr 7 -> ~7 small flushes/wave, +8%).
// Then: 4-round stride-16 LDS tree merge -> radius -> ids in LDS -> loss
// gathers (wave = (seq, k-half)) -> block reduce -> ticket finalize.
// accum[0]=loss, accum[1]=wsum, accum[2]=ticket (zeroed by K1).
// ---------------------------------------------------------------------------
__global__ __launch_bounds__(1024, 4) void mega_kernel(
    const float4* __restrict__ pc4, const float* __restrict__ taufArr,
    const float* __restrict__ flow, const float* __restrict__ wts,
    float* __restrict__ accum, float* __restrict__ out)
{
    __shared__ unsigned uS[1024 * 16];   // 64 KB union: scan bufs / merge / ids
    float* sred = (float*)&uS[1024 * 16 - 32];   // words 16352.. (free region)

    const int tid  = threadIdx.x;
    const int lane = tid & 63;
    const int wv   = __builtin_amdgcn_readfirstlane(tid >> 6);   // 0..15
    const int i    = blockIdx.x * 64 + lane;

    const float4 qv = pc4[i];
    float tauf = taufArr[i];

    unsigned keys[KNN];
#pragma unroll
    for (int t = 0; t < KNN; ++t) keys[t] = 0xFFFFFFFFu;
    int cnt = 0;
    unsigned* buf = &uS[tid * CAPM];

    const int jbeg = wv * SLICE;
    const float4* cb = pc4 + jbeg;       // wave-uniform -> s_load bursts

    // ================= Phase A: filtered scan =============================
    {
        float4 A[BATCH], B[BATCH];
#pragma unroll
        for (int q = 0; q < BATCH; ++q) A[q] = cb[q];

        auto process = [&](const float4* C, int jbase) {
#pragma unroll
            for (int q = 0; q < BATCH; ++q) {
                const float4 c = C[q];
                float dot = fmaf(c.x, qv.x, fmaf(c.y, qv.y, c.z * qv.z));
                float d2p = fmaf(-2.0f, dot, c.w);     // d2 - |q|^2
                if (d2p <= tauf) {                     // exec-masked accept
                    float d2 = fmaxf(d2p + qv.w, 0.0f);
                    buf[cnt] = (__float_as_uint(d2) & 0xFFFFC000u)
                             | (unsigned)(jbeg + jbase + q);
                    ++cnt;
                }
            }
            // headroom: enter batch with cnt <= 6 -> max idx 14 = CAPM-1
            if (cnt >= CAPM - BATCH) {
#pragma unroll 1
                for (int t = 0; t < cnt; ++t) merge_one(keys, buf[t]);
                cnt = 0;
                float d16n = __uint_as_float(keys[KNN - 1] & 0xFFFFC000u);
                tauf = fminf(tauf, fmaf(d16n, 1.0002f, 1e-6f) - qv.w);
            }
        };

#pragma unroll 1
        for (int jo = 0; jo < SLICE; jo += 2 * BATCH) {
#pragma unroll
            for (int q = 0; q < BATCH; ++q) B[q] = cb[jo + BATCH + q];
            process(A, jo);
            if (jo + 2 * BATCH < SLICE) {
#pragma unroll
                for (int q = 0; q < BATCH; ++q) A[q] = cb[jo + 2 * BATCH + q];
            }
            process(B, jo + BATCH);
        }
#pragma unroll 1
        for (int t = 0; t < cnt; ++t) merge_one(keys, buf[t]);
    }
    __syncthreads();   // scan buffers dead; reuse uS as merge slots

    // ================= Phase B: tree merge + radius -> ids ================
#pragma unroll
    for (int t = 0; t < KNN; ++t) uS[tid * 16 + t] = keys[t];
    __syncthreads();
    if (wv < 8) {
        const unsigned* p = &uS[(tid + 512) * 16];
#pragma unroll
        for (int t = 0; t < KNN; ++t) merge_one(keys, p[t]);
#pragma unroll
        for (int t = 0; t < KNN; ++t) uS[tid * 16 + t] = keys[t];
    }
    __syncthreads();
    if (wv < 4) {
        const unsigned* p = &uS[(tid + 256) * 16];
#pragma unroll
        for (int t = 0; t < KNN; ++t) merge_one(keys, p[t]);
#pragma unroll
        for (int t = 0; t < KNN; ++t) uS[tid * 16 + t] = keys[t];
    }
    __syncthreads();
    if (wv < 2) {
        const unsigned* p = &uS[(tid + 128) * 16];
#pragma unroll
        for (int t = 0; t < KNN; ++t) merge_one(keys, p[t]);
#pragma unroll
        for (int t = 0; t < KNN; ++t) uS[tid * 16 + t] = keys[t];
    }
    __syncthreads();
    if (wv == 0) {
        const unsigned* p = &uS[(tid + 64) * 16];
#pragma unroll
        for (int t = 0; t < KNN; ++t) merge_one(keys, p[t]);
        const int id0 = (int)(keys[0] & 0x3FFFu);   // nearest (self)
#pragma unroll
        for (int t = 0; t < KNN; ++t) {
            float d2t = __uint_as_float(keys[t] & 0xFFFFC000u);
            int   j   = (int)(keys[t] & 0x3FFFu);
            uS[lane * 16 + t] = (unsigned)((d2t > 1.0f) ? id0 : j);
        }
    }
    __syncthreads();

    // ================= Phase C: loss + reduce + finalize ==================
    {
        const int s  = wv & 7;
        const int kh = wv >> 3;
        const float* fs = flow + (size_t)s * NPTS * 3;
        const float fx = fs[3 * i + 0];
        const float fy = fs[3 * i + 1];
        const float fz = fs[3 * i + 2];

        float sum = 0.0f;
#pragma unroll
        for (int z = 0; z < 8; ++z) {
            int j = (int)uS[lane * 16 + kh * 8 + z];
            float dx = fx - fs[3 * j + 0];
            float dy = fy - fs[3 * j + 1];
            float dz = fz - fs[3 * j + 2];
            float sq = fmaf(dx, dx, fmaf(dy, dy, dz * dz));
            sum += (sq > 0.0f) ? sqrtf(sq) : 0.0f;
        }

        float contrib = wts[i] * sum;
#pragma unroll
        for (int off = 32; off > 0; off >>= 1) contrib += __shfl_down(contrib, off);
        if (lane == 0) sred[wv] = contrib;

        if (wv == 0) {                       // weight sum, once per block
            float wi = wts[i];
#pragma unroll
            for (int off = 32; off > 0; off >>= 1) wi += __shfl_down(wi, off);
            if (lane == 0) atomicAdd(&accum[1], wi);
        }
        __syncthreads();

        if (tid == 0) {
            float c = 0.0f;
#pragma unroll
            for (int t = 0; t < NW; ++t) c += sred[t];
            atomicAdd(&accum[0], c);
            __threadfence();
            unsigned ticket = atomicAdd((unsigned*)&accum[2], 1u);
            if (ticket == gridDim.x - 1) {   // last block finalizes
                float a  = atomicAdd(&accum[0], 0.0f);   // coherent read
                float ws = atomicAdd(&accum[1], 0.0f);
                float v  = a / (float)(KNN * SEQV);
                out[0] = (ws > 0.0f) ? (v / ws) : v;
            }
        }
    }
}

extern "C" void kernel_launch(void* const* d_in, const int* in_sizes, int n_in,
                              void* d_out, int out_size, void* d_ws, size_t ws_size,
                              hipStream_t stream)
{
    const float* pc   = (const float*)d_in[0];   // (1, N, 3)
    const float* flow = (const float*)d_in[1];   // (SEQ, N, 3)
    const float* wts  = (const float*)d_in[2];   // (N,)
    float* out = (float*)d_out;

    // layout: accum(256 B) | tauf(64 KB) | pc4(256 KB) — no part[] anymore
    float*  accum = (float*)d_ws;
    float*  tauf  = (float*)((char*)d_ws + 256);
    float4* pc4   = (float4*)((char*)d_ws + 256 + NPTS * 4);

    sample_tau_kernel<<<NPTS / 64, 1024, 0, stream>>>(pc, pc4, tauf, accum);
    mega_kernel<<<NPTS / 64, 1024, 0, stream>>>(pc4, tauf, flow, wts, accum, out);
}

// Round 17
// 242.196 us; speedup vs baseline: 1.0091x; 1.0091x over previous
//
#include <hip/hip_runtime.h>
#include <math.h>

#define NPTS  16384
#define KNN   16
#define SEQV  8
#define NW    16      // waves per block (= partitions per query)
#define SLICE 1024    // candidates per wave slice
#define RUN   256     // cold-sampled per slice in K1 -> 4096-sample
#define BATCH 8
#define CAPM  15      // mega append words/thread (flush thr 7; E[acc]=4 -> safe)

// Transposed LDS slot: row t (0..15), column col (0..1023).
// bank = col mod 32 -> consecutive lanes = consecutive banks = conflict-free.
#define SLOT(arr, t, col) arr[(t) * 1024 + (col)]

__device__ __forceinline__ unsigned umin_(unsigned a, unsigned b) { return a < b ? a : b; }
__device__ __forceinline__ unsigned umax_(unsigned a, unsigned b) { return a > b ? a : b; }

// merge one key into sorted ascending keys[16]
__device__ __forceinline__ void merge_one(unsigned keys[KNN], unsigned kk) {
    if (kk < keys[KNN - 1]) {
#pragma unroll
        for (int u = 0; u < KNN; ++u) {
            unsigned lo = umin_(kk, keys[u]);
            kk = umax_(kk, keys[u]);
            keys[u] = lo;
        }
    }
}

// ---------------------------------------------------------------------------
// K1: 4096-sample tau. Grid 256 x 1024 (16 waves, 4/SIMD, 1 block/CU).
// Wave wv cold-chains the first RUN=256 candidates of chunk [1024*wv, ...)
// for the block's 64 queries (lane = query). 4-round TRANSPOSED LDS tree
// merge (conflict-free) -> tau over the 4096-sample (>= global 16th =>
// exact filter; tight enough that mega's CAP=15 buffers flush rarely:
// accept p ~ 1/256). Also writes pc4 and zeroes accum.
// key = (d2 bits & 0xFFFFC000) | j  (j < 2^14).
// ---------------------------------------------------------------------------
__global__ __launch_bounds__(1024, 4) void sample_tau_kernel(
    const float* __restrict__ pc, float4* __restrict__ pc4,
    float* __restrict__ taufArr, float* __restrict__ accum)
{
    __shared__ unsigned sK[1024 * 16];   // 64 KB exactly

    const int tid  = threadIdx.x;
    const int lane = tid & 63;
    const int wv   = __builtin_amdgcn_readfirstlane(tid >> 6);   // 0..15
    const int i    = blockIdx.x * 64 + lane;

    if (blockIdx.x == 0 && tid == 0) {
        accum[0] = 0.0f; accum[1] = 0.0f;
        ((unsigned*)accum)[2] = 0u; ((unsigned*)accum)[3] = 0u;
    }

    const float qx = pc[3 * i + 0];
    const float qy = pc[3 * i + 1];
    const float qz = pc[3 * i + 2];
    const float q2 = fmaf(qx, qx, fmaf(qy, qy, qz * qz));

    if (wv == 0) pc4[i] = make_float4(qx, qy, qz, q2);

    unsigned keys[KNN];
#pragma unroll
    for (int t = 0; t < KNN; ++t) keys[t] = 0xFFFFFFFFu;

    const int jbeg = wv * SLICE;
    const float* cb = pc + 3 * (size_t)jbeg;      // wave-uniform -> s_load

    float A[3 * BATCH], B[3 * BATCH];
#pragma unroll
    for (int u = 0; u < 3 * BATCH; ++u) A[u] = cb[u];

    auto process = [&](const float* C, int jbase) {
        unsigned kb[BATCH];
#pragma unroll
        for (int q = 0; q < BATCH; ++q) {
            float dx = qx - C[3 * q + 0];
            float dy = qy - C[3 * q + 1];
            float dz = qz - C[3 * q + 2];
            float d2 = fmaf(dx, dx, fmaf(dy, dy, dz * dz));
            kb[q] = (__float_as_uint(d2) & 0xFFFFC000u)
                  | (unsigned)(jbeg + jbase + q);
        }
#pragma unroll
        for (int q = 0; q < BATCH; ++q) merge_one(keys, kb[q]);
    };

#pragma unroll 1
    for (int jo = 0; jo < RUN; jo += 2 * BATCH) {
#pragma unroll
        for (int u = 0; u < 3 * BATCH; ++u) B[u] = cb[3 * (jo + BATCH) + u];
        process(A, jo);
        if (jo + 2 * BATCH < RUN) {
#pragma unroll
            for (int u = 0; u < 3 * BATCH; ++u) A[u] = cb[3 * (jo + 2 * BATCH) + u];
        }
        process(B, jo + BATCH);
    }

    // ---- 4-round transposed tree merge (16 -> 1 lists per query) ----
#pragma unroll
    for (int t = 0; t < KNN; ++t) SLOT(sK, t, tid) = keys[t];
    __syncthreads();
    if (wv < 8) {
#pragma unroll
        for (int t = 0; t < KNN; ++t) merge_one(keys, SLOT(sK, t, tid + 512));
#pragma unroll
        for (int t = 0; t < KNN; ++t) SLOT(sK, t, tid) = keys[t];
    }
    __syncthreads();
    if (wv < 4) {
#pragma unroll
        for (int t = 0; t < KNN; ++t) merge_one(keys, SLOT(sK, t, tid + 256));
#pragma unroll
        for (int t = 0; t < KNN; ++t) SLOT(sK, t, tid) = keys[t];
    }
    __syncthreads();
    if (wv < 2) {
#pragma unroll
        for (int t = 0; t < KNN; ++t) merge_one(keys, SLOT(sK, t, tid + 128));
#pragma unroll
        for (int t = 0; t < KNN; ++t) SLOT(sK, t, tid) = keys[t];
    }
    __syncthreads();
    if (wv == 0) {
#pragma unroll
        for (int t = 0; t < KNN; ++t) merge_one(keys, SLOT(sK, t, tid + 64));
        const float d16 = __uint_as_float(keys[KNN - 1] & 0xFFFFC000u);
        // margin covers fma/truncation rounding -> provably exact filter
        taufArr[i] = fmaf(d16, 1.0002f, 1e-6f) - q2;
    }
}

// ---------------------------------------------------------------------------
// K2: mega = filtered scan + tree merge + radius + loss + finalize.
// Grid 256 x 1024 (1 block/CU, 4 waves/SIMD — R9's proven concurrency).
// Block owns queries [64bx, 64bx+64) (lane = query); wave wv scans slice
// [1024wv, +1024) with the R9 scan (SGPR batches, ping-pong, exec-masked
// LDS append stride-15, flush-tighten). CAP=15 safe: tau from 4096-sample
// (E[accepts]=4, flush thr 7 -> ~7 cheap flushes/wave). Then: 4-round
// TRANSPOSED tree merge (conflict-free) -> radius -> ids (rows, cols 0..63)
// -> loss gathers (wave = (seq, k-half)) -> block reduce -> ticket finalize.
// accum[0]=loss, accum[1]=wsum, accum[2]=ticket (zeroed by K1).
// ---------------------------------------------------------------------------
__global__ __launch_bounds__(1024, 4) void mega_kernel(
    const float4* __restrict__ pc4, const float* __restrict__ taufArr,
    const float* __restrict__ flow, const float* __restrict__ wts,
    float* __restrict__ accum, float* __restrict__ out)
{
    __shared__ unsigned uS[1024 * 16];   // 64 KB union: scan bufs / merge / ids
    // sred: row 15, cols 1000.. (never collides with ids at cols 0..63)
    float* sred = (float*)&uS[15 * 1024 + 1000];

    const int tid  = threadIdx.x;
    const int lane = tid & 63;
    const int wv   = __builtin_amdgcn_readfirstlane(tid >> 6);   // 0..15
    const int i    = blockIdx.x * 64 + lane;

    const float4 qv = pc4[i];
    float tauf = taufArr[i];

    unsigned keys[KNN];
#pragma unroll
    for (int t = 0; t < KNN; ++t) keys[t] = 0xFFFFFFFFu;
    int cnt = 0;
    unsigned* buf = &uS[tid * CAPM];     // stride 15 (odd) -> spread banks

    const int jbeg = wv * SLICE;
    const float4* cb = pc4 + jbeg;       // wave-uniform -> s_load bursts

    // ================= Phase A: filtered scan =============================
    {
        float4 A[BATCH], B[BATCH];
#pragma unroll
        for (int q = 0; q < BATCH; ++q) A[q] = cb[q];

        auto process = [&](const float4* C, int jbase) {
#pragma unroll
            for (int q = 0; q < BATCH; ++q) {
                const float4 c = C[q];
                float dot = fmaf(c.x, qv.x, fmaf(c.y, qv.y, c.z * qv.z));
                float d2p = fmaf(-2.0f, dot, c.w);     // d2 - |q|^2
                if (d2p <= tauf) {                     // exec-masked accept
                    float d2 = fmaxf(d2p + qv.w, 0.0f);
                    buf[cnt] = (__float_as_uint(d2) & 0xFFFFC000u)
                             | (unsigned)(jbeg + jbase + q);
                    ++cnt;
                }
            }
            // headroom: enter batch with cnt <= 6 -> max idx 14 = CAPM-1
            if (cnt >= CAPM - BATCH) {
#pragma unroll 1
                for (int t = 0; t < cnt; ++t) merge_one(keys, buf[t]);
                cnt = 0;
                float d16n = __uint_as_float(keys[KNN - 1] & 0xFFFFC000u);
                tauf = fminf(tauf, fmaf(d16n, 1.0002f, 1e-6f) - qv.w);
            }
        };

#pragma unroll 1
        for (int jo = 0; jo < SLICE; jo += 2 * BATCH) {
#pragma unroll
            for (int q = 0; q < BATCH; ++q) B[q] = cb[jo + BATCH + q];
            process(A, jo);
            if (jo + 2 * BATCH < SLICE) {
#pragma unroll
                for (int q = 0; q < BATCH; ++q) A[q] = cb[jo + 2 * BATCH + q];
            }
            process(B, jo + BATCH);
        }
#pragma unroll 1
        for (int t = 0; t < cnt; ++t) merge_one(keys, buf[t]);
    }
    __syncthreads();   // scan buffers dead; reuse uS as transposed merge slots

    // ================= Phase B: tree merge + radius -> ids ================
#pragma unroll
    for (int t = 0; t < KNN; ++t) SLOT(uS, t, tid) = keys[t];
    __syncthreads();
    if (wv < 8) {
#pragma unroll
        for (int t = 0; t < KNN; ++t) merge_one(keys, SLOT(uS, t, tid + 512));
#pragma unroll
        for (int t = 0; t < KNN; ++t) SLOT(uS, t, tid) = keys[t];
    }
    __syncthreads();
    if (wv < 4) {
#pragma unroll
        for (int t = 0; t < KNN; ++t) merge_one(keys, SLOT(uS, t, tid + 256));
#pragma unroll
        for (int t = 0; t < KNN; ++t) SLOT(uS, t, tid) = keys[t];
    }
    __syncthreads();
    if (wv < 2) {
#pragma unroll
        for (int t = 0; t < KNN; ++t) merge_one(keys, SLOT(uS, t, tid + 128));
#pragma unroll
        for (int t = 0; t < KNN; ++t) SLOT(uS, t, tid) = keys[t];
    }
    __syncthreads();
    if (wv == 0) {
#pragma unroll
        for (int t = 0; t < KNN; ++t) merge_one(keys, SLOT(uS, t, tid + 64));
        const int id0 = (int)(keys[0] & 0x3FFFu);   // nearest (self)
#pragma unroll
        for (int t = 0; t < KNN; ++t) {
            float d2t = __uint_as_float(keys[t] & 0xFFFFC000u);
            int   j   = (int)(keys[t] & 0x3FFFu);
            SLOT(uS, t, lane) = (unsigned)((d2t > 1.0f) ? id0 : j);
        }
    }
    __syncthreads();

    // ================= Phase C: loss + reduce + finalize ==================
    {
        const int s  = wv & 7;
        const int kh = wv >> 3;
        const float* fs = flow + (size_t)s * NPTS * 3;
        const float fx = fs[3 * i + 0];
        const float fy = fs[3 * i + 1];
        const float fz = fs[3 * i + 2];

        float sum = 0.0f;
#pragma unroll
        for (int z = 0; z < 8; ++z) {
            int j = (int)SLOT(uS, kh * 8 + z, lane);   // conflict-free row read
            float dx = fx - fs[3 * j + 0];
            float dy = fy - fs[3 * j + 1];
            float dz = fz - fs[3 * j + 2];
            float sq = fmaf(dx, dx, fmaf(dy, dy, dz * dz));
            sum += (sq > 0.0f) ? sqrtf(sq) : 0.0f;
        }

        float contrib = wts[i] * sum;
#pragma unroll
        for (int off = 32; off > 0; off >>= 1) contrib += __shfl_down(contrib, off);
        if (lane == 0) sred[wv] = contrib;

        if (wv == 0) {                       // weight sum, once per block
            float wi = wts[i];
#pragma unroll
            for (int off = 32; off > 0; off >>= 1) wi += __shfl_down(wi, off);
            if (lane == 0) atomicAdd(&accum[1], wi);
        }
        __syncthreads();

        if (tid == 0) {
            float c = 0.0f;
#pragma unroll
            for (int t = 0; t < NW; ++t) c += sred[t];
            atomicAdd(&accum[0], c);
            __threadfence();
            unsigned ticket = atomicAdd((unsigned*)&accum[2], 1u);
            if (ticket == gridDim.x - 1) {   // last block finalizes
                float a  = atomicAdd(&accum[0], 0.0f);   // coherent read
                float ws = atomicAdd(&accum[1], 0.0f);
                float v  = a / (float)(KNN * SEQV);
                out[0] = (ws > 0.0f) ? (v / ws) : v;
            }
        }
    }
}

extern "C" void kernel_launch(void* const* d_in, const int* in_sizes, int n_in,
                              void* d_out, int out_size, void* d_ws, size_t ws_size,
                              hipStream_t stream)
{
    const float* pc   = (const float*)d_in[0];   // (1, N, 3)
    const float* flow = (const float*)d_in[1];   // (SEQ, N, 3)
    const float* wts  = (const float*)d_in[2];   // (N,)
    float* out = (float*)d_out;

    // layout: accum(256 B) | tauf(64 KB) | pc4(256 KB) — no part[] anymore
    float*  accum = (float*)d_ws;
    float*  tauf  = (float*)((char*)d_ws + 256);
    float4* pc4   = (float4*)((char*)d_ws + 256 + NPTS * 4);

    sample_tau_kernel<<<NPTS / 64, 1024, 0, stream>>>(pc, pc4, tauf, accum);
    mega_kernel<<<NPTS / 64, 1024, 0, stream>>>(pc4, tauf, flow, wts, accum, out);
}

// Round 18
// 222.012 us; speedup vs baseline: 1.1008x; 1.0909x over previous
//
#include <hip/hip_runtime.h>
#include <math.h>

#define NPTS  16384
#define KNN   16
#define SEQV  8
#define NW    16      // waves per block
#define SLICE 1024    // candidates per wave slice
#define S1    64      // stage-1 cold sample per slice  -> 1024-sample
#define S2    256     // total sample per slice          -> 4096-sample
#define BATCH 8
#define BUFW  15      // K1 stage-2 append words/thread (flush thr 7; E=3)
#define CAPM  15      // mega append words/thread (flush thr 7; E=4 w/ 4096-tau)

// Transposed LDS slot: row t (0..15), column col (0..1023).
// bank = col mod 32 -> consecutive lanes = consecutive banks = conflict-free.
#define SLOT(arr, t, col) arr[(t) * 1024 + (col)]

__device__ __forceinline__ unsigned umin_(unsigned a, unsigned b) { return a < b ? a : b; }
__device__ __forceinline__ unsigned umax_(unsigned a, unsigned b) { return a > b ? a : b; }

// merge one key into sorted ascending keys[16]
__device__ __forceinline__ void merge_one(unsigned keys[KNN], unsigned kk) {
    if (kk < keys[KNN - 1]) {
#pragma unroll
        for (int u = 0; u < KNN; ++u) {
            unsigned lo = umin_(kk, keys[u]);
            kk = umax_(kk, keys[u]);
            keys[u] = lo;
        }
    }
}

// ---------------------------------------------------------------------------
// K1: two-stage 4096-sample tau ("sample the sample"). Grid 256 x 1024.
// Stage 1: wave wv cold-chains the first S1=64 of slice [1024wv,...) ->
//   tree merge -> tau1 = margined d16 of the 1024-sample (d2 space).
// Stage 2: filtered scan of slice cands [64,256) through stride-15 LDS
//   append buffers (accept p=1/64 -> E=3/lane, flush thr 7 -> storm-free),
//   wv0 keeps its stage-1 merged keys (1024-sample top16) as its base ->
//   second tree merge = EXACT top-16 of the 4096-sample -> taufArr.
// Cold-chain work is 4x smaller than R17's K1 (64 vs 256 cands/wave).
// Also writes pc4[i] = (x,y,z,|c|^2); block 0 zeroes accum.
// key = (d2 bits & 0xFFFFC000) | j  (j < 2^14).
// ---------------------------------------------------------------------------
__global__ __launch_bounds__(1024, 4) void sample_tau_kernel(
    const float* __restrict__ pc, float4* __restrict__ pc4,
    float* __restrict__ taufArr, float* __restrict__ accum)
{
    __shared__ unsigned sK[1024 * 16];   // 64 KB union: tree slots / s2 bufs
    // tau1 broadcast area: words 16320..16383 (row 15, cols 960+) — only
    // alive between tree-1 and tree-2, never concurrent with bufs [0,15360).
    float* sTau1 = (float*)&sK[16320];

    const int tid  = threadIdx.x;
    const int lane = tid & 63;
    const int wv   = __builtin_amdgcn_readfirstlane(tid >> 6);   // 0..15
    const int i    = blockIdx.x * 64 + lane;

    if (blockIdx.x == 0 && tid == 0) {
        accum[0] = 0.0f; accum[1] = 0.0f;
        ((unsigned*)accum)[2] = 0u; ((unsigned*)accum)[3] = 0u;
    }

    const float qx = pc[3 * i + 0];
    const float qy = pc[3 * i + 1];
    const float qz = pc[3 * i + 2];
    const float q2 = fmaf(qx, qx, fmaf(qy, qy, qz * qz));

    if (wv == 0) pc4[i] = make_float4(qx, qy, qz, q2);

    unsigned keys[KNN];
#pragma unroll
    for (int t = 0; t < KNN; ++t) keys[t] = 0xFFFFFFFFu;

    const int jbeg = wv * SLICE;
    const float* cb = pc + 3 * (size_t)jbeg;      // wave-uniform -> s_load

    float A[3 * BATCH], B[3 * BATCH];

    // ---------------- stage 1: cold chain first S1 ----------------
    {
#pragma unroll
        for (int u = 0; u < 3 * BATCH; ++u) A[u] = cb[u];

        auto proc1 = [&](const float* C, int jbase) {
            unsigned kb[BATCH];
#pragma unroll
            for (int q = 0; q < BATCH; ++q) {
                float dx = qx - C[3 * q + 0];
                float dy = qy - C[3 * q + 1];
                float dz = qz - C[3 * q + 2];
                float d2 = fmaf(dx, dx, fmaf(dy, dy, dz * dz));
                kb[q] = (__float_as_uint(d2) & 0xFFFFC000u)
                      | (unsigned)(jbeg + jbase + q);
            }
#pragma unroll
            for (int q = 0; q < BATCH; ++q) merge_one(keys, kb[q]);
        };

#pragma unroll 1
        for (int jo = 0; jo < S1; jo += 2 * BATCH) {
#pragma unroll
            for (int u = 0; u < 3 * BATCH; ++u) B[u] = cb[3 * (jo + BATCH) + u];
            proc1(A, jo);
            if (jo + 2 * BATCH < S1) {
#pragma unroll
                for (int u = 0; u < 3 * BATCH; ++u) A[u] = cb[3 * (jo + 2 * BATCH) + u];
            }
            proc1(B, jo + BATCH);
        }
    }

    // ---------------- tree merge 1 -> tau1 (1024-sample) ----------------
#pragma unroll
    for (int t = 0; t < KNN; ++t) SLOT(sK, t, tid) = keys[t];
    __syncthreads();
    if (wv < 8) {
#pragma unroll
        for (int t = 0; t < KNN; ++t) merge_one(keys, SLOT(sK, t, tid + 512));
#pragma unroll
        for (int t = 0; t < KNN; ++t) SLOT(sK, t, tid) = keys[t];
    }
    __syncthreads();
    if (wv < 4) {
#pragma unroll
        for (int t = 0; t < KNN; ++t) merge_one(keys, SLOT(sK, t, tid + 256));
#pragma unroll
        for (int t = 0; t < KNN; ++t) SLOT(sK, t, tid) = keys[t];
    }
    __syncthreads();
    if (wv < 2) {
#pragma unroll
        for (int t = 0; t < KNN; ++t) merge_one(keys, SLOT(sK, t, tid + 128));
#pragma unroll
        for (int t = 0; t < KNN; ++t) SLOT(sK, t, tid) = keys[t];
    }
    __syncthreads();
    if (wv == 0) {
#pragma unroll
        for (int t = 0; t < KNN; ++t) merge_one(keys, SLOT(sK, t, tid + 64));
        const float d16 = __uint_as_float(keys[KNN - 1] & 0xFFFFC000u);
        // margin covers fma/truncation rounding -> filter provably keeps
        // every key that could be in the sample top-16
        sTau1[lane] = fmaf(d16, 1.0002f, 1e-6f);
    }
    __syncthreads();

    // ---------------- stage 2: filtered scan of [S1, S2) ----------------
    {
        float tau1d = sTau1[lane];     // 2 lanes/bank -> free
        if (wv != 0) {                 // wv0 keeps 1024-sample top16 as base
#pragma unroll
            for (int t = 0; t < KNN; ++t) keys[t] = 0xFFFFFFFFu;
        }
        int cnt = 0;
        unsigned* buf = &sK[tid * BUFW];   // stride 15 (odd) -> spread banks

#pragma unroll
        for (int u = 0; u < 3 * BATCH; ++u) A[u] = cb[3 * S1 + u];

        auto proc2 = [&](const float* C, int jbase) {
#pragma unroll
            for (int q = 0; q < BATCH; ++q) {
                float dx = qx - C[3 * q + 0];
                float dy = qy - C[3 * q + 1];
                float dz = qz - C[3 * q + 2];
                float d2 = fmaf(dx, dx, fmaf(dy, dy, dz * dz));
                if (d2 <= tau1d) {             // exec-masked accept
                    buf[cnt] = (__float_as_uint(d2) & 0xFFFFC000u)
                             | (unsigned)(jbeg + jbase + q);
                    ++cnt;
                }
            }
            // headroom: enter batch with cnt <= 6 -> max idx 14 = BUFW-1
            if (cnt >= BUFW - BATCH) {
#pragma unroll 1
                for (int t = 0; t < cnt; ++t) merge_one(keys, buf[t]);
                cnt = 0;
                float d16n = __uint_as_float(keys[KNN - 1] & 0xFFFFC000u);
                tau1d = fminf(tau1d, fmaf(d16n, 1.0002f, 1e-6f));
            }
        };

#pragma unroll 1
        for (int jo = S1; jo < S2; jo += 2 * BATCH) {
#pragma unroll
            for (int u = 0; u < 3 * BATCH; ++u) B[u] = cb[3 * (jo + BATCH) + u];
            proc2(A, jo);
            if (jo + 2 * BATCH < S2) {
#pragma unroll
                for (int u = 0; u < 3 * BATCH; ++u) A[u] = cb[3 * (jo + 2 * BATCH) + u];
            }
            proc2(B, jo + BATCH);
        }
#pragma unroll 1
        for (int t = 0; t < cnt; ++t) merge_one(keys, buf[t]);
    }
    __syncthreads();   // bufs + sTau1 dead; reuse slots for tree 2

    // ---------------- tree merge 2 -> exact 4096-sample tau --------------
#pragma unroll
    for (int t = 0; t < KNN; ++t) SLOT(sK, t, tid) = keys[t];
    __syncthreads();
    if (wv < 8) {
#pragma unroll
        for (int t = 0; t < KNN; ++t) merge_one(keys, SLOT(sK, t, tid + 512));
#pragma unroll
        for (int t = 0; t < KNN; ++t) SLOT(sK, t, tid) = keys[t];
    }
    __syncthreads();
    if (wv < 4) {
#pragma unroll
        for (int t = 0; t < KNN; ++t) merge_one(keys, SLOT(sK, t, tid + 256));
#pragma unroll
        for (int t = 0; t < KNN; ++t) SLOT(sK, t, tid) = keys[t];
    }
    __syncthreads();
    if (wv < 2) {
#pragma unroll
        for (int t = 0; t < KNN; ++t) merge_one(keys, SLOT(sK, t, tid + 128));
#pragma unroll
        for (int t = 0; t < KNN; ++t) SLOT(sK, t, tid) = keys[t];
    }
    __syncthreads();
    if (wv == 0) {
#pragma unroll
        for (int t = 0; t < KNN; ++t) merge_one(keys, SLOT(sK, t, tid + 64));
        const float d16 = __uint_as_float(keys[KNN - 1] & 0xFFFFC000u);
        taufArr[i] = fmaf(d16, 1.0002f, 1e-6f) - q2;   // d2p-space bound
    }
}

// ---------------------------------------------------------------------------
// K2: mega (R17-verbatim, measured 108 us / 1409 conflicts) = filtered scan
// + transposed tree merge + radius + loss + finalize. Grid 256 x 1024.
// accum[0]=loss, accum[1]=wsum, accum[2]=ticket (zeroed by K1).
// ---------------------------------------------------------------------------
__global__ __launch_bounds__(1024, 4) void mega_kernel(
    const float4* __restrict__ pc4, const float* __restrict__ taufArr,
    const float* __restrict__ flow, const float* __restrict__ wts,
    float* __restrict__ accum, float* __restrict__ out)
{
    __shared__ unsigned uS[1024 * 16];   // 64 KB union: scan bufs / merge / ids
    float* sred = (float*)&uS[15 * 1024 + 1000];

    const int tid  = threadIdx.x;
    const int lane = tid & 63;
    const int wv   = __builtin_amdgcn_readfirstlane(tid >> 6);   // 0..15
    const int i    = blockIdx.x * 64 + lane;

    const float4 qv = pc4[i];
    float tauf = taufArr[i];

    unsigned keys[KNN];
#pragma unroll
    for (int t = 0; t < KNN; ++t) keys[t] = 0xFFFFFFFFu;
    int cnt = 0;
    unsigned* buf = &uS[tid * CAPM];     // stride 15 (odd) -> spread banks

    const int jbeg = wv * SLICE;
    const float4* cb = pc4 + jbeg;       // wave-uniform -> s_load bursts

    // ================= Phase A: filtered scan =============================
    {
        float4 A[BATCH], B[BATCH];
#pragma unroll
        for (int q = 0; q < BATCH; ++q) A[q] = cb[q];

        auto process = [&](const float4* C, int jbase) {
#pragma unroll
            for (int q = 0; q < BATCH; ++q) {
                const float4 c = C[q];
                float dot = fmaf(c.x, qv.x, fmaf(c.y, qv.y, c.z * qv.z));
                float d2p = fmaf(-2.0f, dot, c.w);     // d2 - |q|^2
                if (d2p <= tauf) {                     // exec-masked accept
                    float d2 = fmaxf(d2p + qv.w, 0.0f);
                    buf[cnt] = (__float_as_uint(d2) & 0xFFFFC000u)
                             | (unsigned)(jbeg + jbase + q);
                    ++cnt;
                }
            }
            // headroom: enter batch with cnt <= 6 -> max idx 14 = CAPM-1
            if (cnt >= CAPM - BATCH) {
#pragma unroll 1
                for (int t = 0; t < cnt; ++t) merge_one(keys, buf[t]);
                cnt = 0;
                float d16n = __uint_as_float(keys[KNN - 1] & 0xFFFFC000u);
                tauf = fminf(tauf, fmaf(d16n, 1.0002f, 1e-6f) - qv.w);
            }
        };

#pragma unroll 1
        for (int jo = 0; jo < SLICE; jo += 2 * BATCH) {
#pragma unroll
            for (int q = 0; q < BATCH; ++q) B[q] = cb[jo + BATCH + q];
            process(A, jo);
            if (jo + 2 * BATCH < SLICE) {
#pragma unroll
                for (int q = 0; q < BATCH; ++q) A[q] = cb[jo + 2 * BATCH + q];
            }
            process(B, jo + BATCH);
        }
#pragma unroll 1
        for (int t = 0; t < cnt; ++t) merge_one(keys, buf[t]);
    }
    __syncthreads();   // scan buffers dead; reuse uS as transposed merge slots

    // ================= Phase B: tree merge + radius -> ids ================
#pragma unroll
    for (int t = 0; t < KNN; ++t) SLOT(uS, t, tid) = keys[t];
    __syncthreads();
    if (wv < 8) {
#pragma unroll
        for (int t = 0; t < KNN; ++t) merge_one(keys, SLOT(uS, t, tid + 512));
#pragma unroll
        for (int t = 0; t < KNN; ++t) SLOT(uS, t, tid) = keys[t];
    }
    __syncthreads();
    if (wv < 4) {
#pragma unroll
        for (int t = 0; t < KNN; ++t) merge_one(keys, SLOT(uS, t, tid + 256));
#pragma unroll
        for (int t = 0; t < KNN; ++t) SLOT(uS, t, tid) = keys[t];
    }
    __syncthreads();
    if (wv < 2) {
#pragma unroll
        for (int t = 0; t < KNN; ++t) merge_one(keys, SLOT(uS, t, tid + 128));
#pragma unroll
        for (int t = 0; t < KNN; ++t) SLOT(uS, t, tid) = keys[t];
    }
    __syncthreads();
    if (wv == 0) {
#pragma unroll
        for (int t = 0; t < KNN; ++t) merge_one(keys, SLOT(uS, t, tid + 64));
        const int id0 = (int)(keys[0] & 0x3FFFu);   // nearest (self)
#pragma unroll
        for (int t = 0; t < KNN; ++t) {
            float d2t = __uint_as_float(keys[t] & 0xFFFFC000u);
            int   j   = (int)(keys[t] & 0x3FFFu);
            SLOT(uS, t, lane) = (unsigned)((d2t > 1.0f) ? id0 : j);
        }
    }
    __syncthreads();

    // ================= Phase C: loss + reduce + finalize ==================
    {
        const int s  = wv & 7;
        const int kh = wv >> 3;
        const float* fs = flow + (size_t)s * NPTS * 3;
        const float fx = fs[3 * i + 0];
        const float fy = fs[3 * i + 1];
        const float fz = fs[3 * i + 2];

        float sum = 0.0f;
#pragma unroll
        for (int z = 0; z < 8; ++z) {
            int j = (int)SLOT(uS, kh * 8 + z, lane);   // conflict-free
            float dx = fx - fs[3 * j + 0];
            float dy = fy - fs[3 * j + 1];
            float dz = fz - fs[3 * j + 2];
            float sq = fmaf(dx, dx, fmaf(dy, dy, dz * dz));
            sum += (sq > 0.0f) ? sqrtf(sq) : 0.0f;
        }

        float contrib = wts[i] * sum;
#pragma unroll
        for (int off = 32; off > 0; off >>= 1) contrib += __shfl_down(contrib, off);
        if (lane == 0) sred[wv] = contrib;

        if (wv == 0) {                       // weight sum, once per block
            float wi = wts[i];
#pragma unroll
            for (int off = 32; off > 0; off >>= 1) wi += __shfl_down(wi, off);
            if (lane == 0) atomicAdd(&accum[1], wi);
        }
        __syncthreads();

        if (tid == 0) {
            float c = 0.0f;
#pragma unroll
            for (int t = 0; t < NW; ++t) c += sred[t];
            atomicAdd(&accum[0], c);
            __threadfence();
            unsigned ticket = atomicAdd((unsigned*)&accum[2], 1u);
            if (ticket == gridDim.x - 1) {   // last block finalizes
                float a  = atomicAdd(&accum[0], 0.0f);   // coherent read
                float ws = atomicAdd(&accum[1], 0.0f);
                float v  = a / (float)(KNN * SEQV);
                out[0] = (ws > 0.0f) ? (v / ws) : v;
            }
        }
    }
}

extern "C" void kernel_launch(void* const* d_in, const int* in_sizes, int n_in,
                              void* d_out, int out_size, void* d_ws, size_t ws_size,
                              hipStream_t stream)
{
    const float* pc   = (const float*)d_in[0];   // (1, N, 3)
    const float* flow = (const float*)d_in[1];   // (SEQ, N, 3)
    const float* wts  = (const float*)d_in[2];   // (N,)
    float* out = (float*)d_out;

    // layout: accum(256 B) | tauf(64 KB) | pc4(256 KB)
    float*  accum = (float*)d_ws;
    float*  tauf  = (float*)((char*)d_ws + 256);
    float4* pc4   = (float4*)((char*)d_ws + 256 + NPTS * 4);

    sample_tau_kernel<<<NPTS / 64, 1024, 0, stream>>>(pc, pc4, tauf, accum);
    mega_kernel<<<NPTS / 64, 1024, 0, stream>>>(pc4, tauf, flow, wts, accum, out);
}